// Round 3
// baseline (50.205 us; speedup 1.0000x reference)
//
#include <hip/hip_runtime.h>
#include <math.h>

// Problem sizes (fixed by reference setup_inputs)
#define NP      (128 * 196)   // 25088 patches
#define PATCH   768           // elements per patch
#define ND      128           // contrastive N
#define DD      256           // contrastive D
#define TEMP_INV 10.0f        // 1 / 0.1
#define COS_EPS_F 1e-8f

#define NPW     4                 // patches per wave (ping-pong pipelined)
#define NWAVE_R (NP / NPW)        // 6272 recon waves
#define NB_R    (NWAVE_R / 4)     // 1568 recon blocks (4 waves each)
#define NB_C    32                // contrastive blocks (4 rows each -> 128 rows)

__device__ __forceinline__ float wave_sum(float v) {
#pragma unroll
    for (int o = 32; o; o >>= 1) v += __shfl_xor(v, o);
    return v;
}
__device__ __forceinline__ float wave_max(float v) {
#pragma unroll
    for (int o = 32; o; o >>= 1) v = fmaxf(v, __shfl_xor(v, o));
    return v;
}
__device__ __forceinline__ float dot4(float4 a, float4 b) {
    return a.x * b.x + a.y * b.y + a.z * b.z + a.w * b.w;
}

// ws layout (floats):
//   [0          .. NWAVE_R)     per-wave weighted-loss partial
//   [NWAVE_R    .. 2*NWAVE_R)   per-wave mask-sum partial
//   [2*NWAVE_R  .. +128)        per-row contrastive contribution (lse_i - S_ii/T)
__global__ __launch_bounds__(256) void partials_kernel(
    const float* __restrict__ preds,   // student_prob [128,256]
    const float* __restrict__ tgts,    // teacher_prob [128,256]
    const float* __restrict__ rt,      // reconstruct_target [B,L,P]
    const float* __restrict__ rp,      // reconstruct_pred   [B,L,P]
    const float* __restrict__ mask,    // [B,L]
    float* __restrict__ ws)
{
    const int tid  = threadIdx.x;
    const int w    = tid >> 6;
    const int lane = tid & 63;
    const int blk  = blockIdx.x;

    if (blk < NB_R) {
        // -------- reconstruction: 4 patches/wave, ping-pong prefetch --------
        const int gw = blk * 4 + w;          // 0..6271
        const int p0 = gw * NPW;
        const float4* t4 = (const float4*)(rt + (size_t)p0 * PATCH) + lane;
        const float4* q4 = (const float4*)(rp + (size_t)p0 * PATCH) + lane;

        float4 TA[3], QA[3], TB[3], QB[3];
        float mk[NPW];
#pragma unroll
        for (int p = 0; p < NPW; ++p) mk[p] = mask[p0 + p];   // broadcast loads
        // prefetch patch 0 into A
#pragma unroll
        for (int q = 0; q < 3; ++q) { TA[q] = t4[q * 64]; QA[q] = q4[q * 64]; }

        float acc_l = 0.f;

#define PREFETCH(Tb, Qb, pn)                                          \
        {                                                             \
            const float4* tn = t4 + (pn) * (PATCH / 4);               \
            const float4* qn = q4 + (pn) * (PATCH / 4);               \
            _Pragma("unroll")                                         \
            for (int q = 0; q < 3; ++q) {                             \
                Tb[q] = tn[q * 64]; Qb[q] = qn[q * 64];               \
            }                                                         \
        }

#define COMPUTE_PATCH(Tb, Qb, mval)                                   \
        {                                                             \
            float s = 0.f, ssq = 0.f, sp = 0.f, spp = 0.f, spt = 0.f; \
            _Pragma("unroll")                                         \
            for (int q = 0; q < 3; ++q) {                             \
                float4 t = Tb[q], pv = Qb[q];                         \
                s   += t.x + t.y + t.z + t.w;                         \
                ssq += dot4(t, t);                                    \
                sp  += pv.x + pv.y + pv.z + pv.w;                     \
                spp += dot4(pv, pv);                                  \
                spt += dot4(pv, t);                                   \
            }                                                         \
            _Pragma("unroll")                                         \
            for (int o = 32; o; o >>= 1) {                            \
                s   += __shfl_xor(s, o);                              \
                ssq += __shfl_xor(ssq, o);                            \
                sp  += __shfl_xor(sp, o);                             \
                spp += __shfl_xor(spp, o);                            \
                spt += __shfl_xor(spt, o);                            \
            }                                                         \
            const float mean = s * (1.0f / PATCH);                    \
            const float cvar = ssq - s * mean;                        \
            const float var  = cvar * (1.0f / (PATCH - 1));           \
            const float rstd = 1.0f / sqrtf(var + 1e-6f);             \
            const float lsum = spp - 2.f * rstd * (spt - mean * sp)   \
                             + rstd * rstd * cvar;                    \
            acc_l += lsum * (1.0f / PATCH) * (mval);                  \
        }

        PREFETCH(TB, QB, 1);
        COMPUTE_PATCH(TA, QA, mk[0]);
        PREFETCH(TA, QA, 2);
        COMPUTE_PATCH(TB, QB, mk[1]);
        PREFETCH(TB, QB, 3);
        COMPUTE_PATCH(TA, QA, mk[2]);
        COMPUTE_PATCH(TB, QB, mk[3]);

#undef PREFETCH
#undef COMPUTE_PATCH

        if (lane == 0) {
            ws[gw]           = acc_l;
            ws[NWAVE_R + gw] = mk[0] + mk[1] + mk[2] + mk[3];
        }
    } else {
        // ---------------- contrastive per-row contributions ----------------
        __shared__ float4 pn4s[4][DD / 4];
        const int cb = blk - NB_R;       // 0..31
        const int i  = cb * 4 + w;       // row 0..127
        const float4* pg = (const float4*)preds;
        const float4* tg = (const float4*)tgts;

        // stage normalized pred row i into LDS (wave-local)
        float4 v = pg[(size_t)i * (DD / 4) + lane];
        float ssp = wave_sum(dot4(v, v));
        float invp = 1.0f / fmaxf(sqrtf(ssp), COS_EPS_F);
        pn4s[w][lane] = make_float4(v.x * invp, v.y * invp, v.z * invp, v.w * invp);
        __syncthreads();

        // lane j reads full teacher row j: accumulate dot AND row norm inline
        const int j1 = lane, j2 = lane + 64;
        float d1 = 0.f, d2 = 0.f, n1 = 0.f, n2 = 0.f;
#pragma unroll 8
        for (int k = 0; k < DD / 4; ++k) {
            float4 c = pn4s[w][k];                 // LDS broadcast
            float4 a = tg[j1 * (DD / 4) + k];
            float4 b = tg[j2 * (DD / 4) + k];
            d1 += dot4(c, a);  n1 += dot4(a, a);
            d2 += dot4(c, b);  n2 += dot4(b, b);
        }
        const float s1 = d1 * (1.0f / fmaxf(sqrtf(n1), COS_EPS_F)) * TEMP_INV;
        const float s2 = d2 * (1.0f / fmaxf(sqrtf(n2), COS_EPS_F)) * TEMP_INV;
        float m = wave_max(fmaxf(s1, s2));
        float sum = wave_sum(expf(s1 - m) + expf(s2 - m));
        const float lse = m + logf(sum);
        const float pos = (i < 64) ? __shfl(s1, i) : __shfl(s2, i - 64);
        if (lane == 0) ws[2 * NWAVE_R + i] = lse - pos;
    }
}

__global__ __launch_bounds__(256) void finalize_kernel(
    const float* __restrict__ ws, float* __restrict__ out)
{
    __shared__ float s_red[12];
    const int tid = threadIdx.x, w = tid >> 6, lane = tid & 63;
    float a = 0.f, b = 0.f, c = 0.f;
    for (int i = tid; i < NWAVE_R; i += 256) {
        a += ws[i];
        b += ws[NWAVE_R + i];
    }
    if (tid < ND) c = ws[2 * NWAVE_R + tid];
    a = wave_sum(a); b = wave_sum(b); c = wave_sum(c);
    if (lane == 0) { s_red[w] = a; s_red[4 + w] = b; s_red[8 + w] = c; }
    __syncthreads();
    if (tid == 0) {
        float la = 0.f, lb = 0.f, lc = 0.f;
#pragma unroll
        for (int k = 0; k < 4; ++k) {
            la += s_red[k]; lb += s_red[4 + k]; lc += s_red[8 + k];
        }
        const float recon = la / lb;
        const float contr = lc / (float)ND;
        out[0] = recon;
        out[1] = contr;
        out[2] = recon + contr;
    }
}

extern "C" void kernel_launch(void* const* d_in, const int* in_sizes, int n_in,
                              void* d_out, int out_size, void* d_ws, size_t ws_size,
                              hipStream_t stream) {
    const float* student = (const float*)d_in[0];
    const float* teacher = (const float*)d_in[1];
    const float* rt      = (const float*)d_in[2];
    const float* rp      = (const float*)d_in[3];
    const float* mask    = (const float*)d_in[4];
    float* ws  = (float*)d_ws;
    float* out = (float*)d_out;

    hipLaunchKernelGGL(partials_kernel, dim3(NB_R + NB_C), dim3(256), 0, stream,
                       student, teacher, rt, rp, mask, ws);
    hipLaunchKernelGGL(finalize_kernel, dim3(1), dim3(256), 0, stream, ws, out);
}